// Round 23
// baseline (69.830 us; speedup 1.0000x reference)
//
#include <hip/hip_runtime.h>
#include <stdint.h>

#define N_ROWS 8192
#define D_DIM  1024
#define NEG_BIG -1e30f
#define NCHUNK 16
#define CHUNK_J 512
#define NTILE 16              // 16 j-tiles of 32 cols per chunk
#define BUFSZ 17408           // 16 KB fp4 tile + 1 KB scale block

typedef __attribute__((ext_vector_type(16))) float f32x16;
typedef __attribute__((ext_vector_type(8)))  int   i32x8;
typedef __attribute__((ext_vector_type(4)))  int   i32x4;
typedef __attribute__((ext_vector_type(2)))  long  long2_t;

// exp(10v - 10) = exp2(v*C - C), raw v_exp_f32
#define EXPC 14.4269504089f
#define EXPRAW(dst, v) { float _a = fmaf((v), EXPC, -EXPC);                 \
    asm("v_exp_f32 %0, %1" : "=v"(dst) : "v"(_a)); }

// branchless sorted insert of v into descending 5-list, med3 form
#define INS5(b0,b1,b2,b3,b4,v) {                        \
    float _n4 = __builtin_amdgcn_fmed3f(b3, (v), b4);   \
    float _n3 = __builtin_amdgcn_fmed3f(b2, (v), b3);   \
    float _n2 = __builtin_amdgcn_fmed3f(b1, (v), b2);   \
    float _n1 = __builtin_amdgcn_fmed3f(b0, (v), b1);   \
    b0 = fmaxf(b0, (v)); b1 = _n1; b2 = _n2; b3 = _n3; b4 = _n4; }

// e2m1 encode of x (pre-scaled by inv = 2^-s): grid {0,.5,1,1.5,2,3,4,6}
static __device__ inline uint32_t enc4(float x, float inv) {
    float q = fabsf(x) * inv;
    uint32_t n = q < 0.25f ? 0u : (q < 0.75f ? 1u : (q < 1.25f ? 2u : (q < 1.75f ? 3u :
                 (q < 2.5f  ? 4u : (q < 3.5f  ? 5u : (q < 5.0f  ? 6u : 7u))))));
    return n | (x < 0.f ? 8u : 0u);
}

// ---------------- K1: normalize -> MX-fp4 (e2m1 + per-32-block E8M0) --------
__global__ __launch_bounds__(256) void norm_kernel(const float* __restrict__ z,
                                                   uint8_t* __restrict__ zn4,
                                                   uint8_t* __restrict__ sbq) {
    int wave = threadIdx.x >> 6;
    int lane = threadIdx.x & 63;
    int row  = blockIdx.x * 4 + wave;
    const float* zr = z + (size_t)row * D_DIM;
    float4 c[4];
    float ss = 0.f;
#pragma unroll
    for (int i = 0; i < 4; ++i) {
        c[i] = *(const float4*)(zr + i * 256 + lane * 4);
        ss += c[i].x*c[i].x + c[i].y*c[i].y + c[i].z*c[i].z + c[i].w*c[i].w;
    }
#pragma unroll
    for (int m = 1; m < 64; m <<= 1) ss += __shfl_xor(ss, m);
    float scale = 1.0f / fmaxf(sqrtf(ss), 1e-12f);
    const int J = row >> 5, r31 = row & 31;
    uint8_t* db = zn4 + (size_t)J * 16384;
    uint8_t* sb = sbq + (size_t)J * 1024;
#pragma unroll
    for (int i = 0; i < 4; ++i) {
        float x0 = c[i].x*scale, x1 = c[i].y*scale, x2 = c[i].z*scale, x3 = c[i].w*scale;
        float am = fmaxf(fmaxf(fabsf(x0), fabsf(x1)), fmaxf(fabsf(x2), fabsf(x3)));
        am = fmaxf(am, __shfl_xor(am, 1));
        am = fmaxf(am, __shfl_xor(am, 2));
        am = fmaxf(am, __shfl_xor(am, 4));
        uint32_t ub = __float_as_uint(am);
        int sbyte = (int)(ub >> 23) - 2 + (((ub & 0x7fffffu) > 0x400000u) ? 1 : 0);
        float inv = __uint_as_float((uint32_t)(254 - sbyte) << 23);   // 2^-s
        uint32_t pk = enc4(x0, inv) | (enc4(x1, inv) << 4)
                    | (enc4(x2, inv) << 8) | (enc4(x3, inv) << 12);
        int m  = i * 4 + (lane >> 4);
        int l2 = r31 + 32 * ((lane >> 3) & 1);
        *(uint16_t*)(db + m * 1024 + l2 * 16 + 2 * (lane & 7)) = (uint16_t)pk;
        if ((lane & 7) == 0) {
            int j = lane >> 3;
            sb[(size_t)(r31 + 32 * (j & 1)) * 16 + i * 4 + (j >> 1)] = (uint8_t)sbyte;
        }
    }
}

// ---------------- K2: fused MX-fp4 sim, DEFERRED epilogue --------------------
// R14 structure + svp deferral (R8's trick, now affordable at fp4: bres=64,
// VGPR~96 < 128 two-wave budget). Tile t's 128-VALU INS5/EXPRAW chain runs on
// tile t+1's svp-independent MFMA window -> breaks the per-wave
// [MFMA burst]->[dependent VALU burst] serialization (the ~800 cyc/tile idle).
// svp init NEG_BIG: EXPRAW->0, INS5 no-op -> uniform loop + single flush.
__global__ __launch_bounds__(256, 2) void sim_kernel(const uint8_t* __restrict__ zn4,
                                                     const uint8_t* __restrict__ sbq,
                                                     float* __restrict__ pstats) {
    __shared__ __align__(16) char lds[2 * BUFSZ];
    const int tid  = threadIdx.x;
    const int w    = tid >> 6;
    const int l    = tid & 63;
    const int r32  = l & 31;
    const int h    = l >> 5;
    const int ib   = blockIdx.x >> 4;
    const int ch   = blockIdx.x & 15;
    const int j0c  = ch * CHUNK_J;
    const int i_lane = ib * 128 + w * 32 + r32;
    const int Ii   = ib * 4 + w;                       // i-tile index 0..255
    const int diag_jt = ((Ii >> 4) == ch) ? (Ii & 15) : -1;
    const char* ldsr = lds + l * 16;

#define GLL(SRC, DST) __builtin_amdgcn_global_load_lds(                         \
        (const __attribute__((address_space(1))) uint32_t*)(SRC),               \
        (__attribute__((address_space(3))) uint32_t*)(DST), 16, 0, 0)

#define STAGE(JTN, BUF) {                                                       \
        const uint8_t* sD_ = zn4 + (size_t)(ch * NTILE + (JTN)) * 16384;        \
        _Pragma("unroll")                                                       \
        for (int mm = 0; mm < 4; ++mm) {                                        \
            int m_ = w * 4 + mm;                                                \
            GLL(sD_ + m_ * 1024 + l * 16, (BUF) + m_ * 1024);                   \
        }                                                                       \
        if (w == 0)                                                             \
            GLL(sbq + (size_t)(ch * NTILE + (JTN)) * 1024 + l * 16,             \
                (BUF) + 16384);                                                 \
    }

    STAGE(0, lds);

    // resident B: 8 packed pairs (even m lower 4 dwords, odd m upper) + scales
    i32x8 bres8[8];
    {
        const uint8_t* rp = zn4 + (size_t)Ii * 16384 + l * 16;
#pragma unroll
        for (int g = 0; g < 8; ++g) {
            *(long2_t*)&bres8[g]       = *(const long2_t*)(rp + (2 * g) * 1024);
            *((long2_t*)&bres8[g] + 1) = *(const long2_t*)(rp + (2 * g + 1) * 1024);
        }
    }
    uint32_t sb_[4];
    {
        const uint32_t* sp = (const uint32_t*)(sbq + (size_t)Ii * 1024 + l * 16);
        sb_[0] = sp[0]; sb_[1] = sp[1]; sb_[2] = sp[2]; sb_[3] = sp[3];
    }

    float s0r = 0.f, s1r = 0.f;
    float b0 = NEG_BIG, b1 = NEG_BIG, b2 = NEG_BIG, b3 = NEG_BIG, b4 = NEG_BIG;
    f32x16 svp;
#pragma unroll
    for (int r = 0; r < 16; ++r) svp[r] = NEG_BIG;
    i32x8 areg0 = {0,0,0,0,0,0,0,0}, areg1 = {0,0,0,0,0,0,0,0};
    i32x8 btmp  = {0,0,0,0,0,0,0,0};

    __syncthreads();

// deferred epilogue: INS5 + EXPRAW on previous tile's masked values
#define EPI5() {                                                                \
        _Pragma("unroll")                                                       \
        for (int r = 0; r < 16; ++r) {                                          \
            float v = svp[r];                                                   \
            INS5(b0, b1, b2, b3, b4, v);                                        \
            float e_; EXPRAW(e_, v);                                            \
            if (r & 1) s1r += e_; else s0r += e_;                               \
        }                                                                       \
    }

// literal-M MFMA macros: opsel args (M)&3 are integer constant expressions
#define MFMA_E(M) {                                                             \
        asm volatile("" : "+v"(bres8[(M) >> 1]));                               \
        *(long2_t*)&areg0 = *(const long2_t*)(ldst_ + (M) * 1024);              \
        acc0 = __builtin_amdgcn_mfma_scale_f32_32x32x64_f8f6f4(                 \
            areg0, bres8[(M) >> 1], acc0, 4, 4,                                 \
            (M) & 3, sa_[(M) >> 2], (M) & 3, sb_[(M) >> 2]); }
#define MFMA_O(M) {                                                             \
        *(long2_t*)&btmp  = *((const long2_t*)&bres8[(M) >> 1] + 1);            \
        *(long2_t*)&areg1 = *(const long2_t*)(ldst_ + (M) * 1024);              \
        acc1 = __builtin_amdgcn_mfma_scale_f32_32x32x64_f8f6f4(                 \
            areg1, btmp, acc1, 4, 4,                                            \
            (M) & 3, sa_[(M) >> 2], (M) & 3, sb_[(M) >> 2]); }

#define TILE_BODY(JT, CUR) {                                                    \
        if ((JT) + 1 < NTILE) STAGE((JT) + 1, lds + ((CUR) ^ BUFSZ));           \
        const char* ldst_ = ldsr + (CUR);                                       \
        uint32_t sa_[4];                                                        \
        {                                                                       \
            i32x4 sv = *(const i32x4*)(lds + (CUR) + 16384 + l * 16);           \
            sa_[0] = sv[0]; sa_[1] = sv[1]; sa_[2] = sv[2]; sa_[3] = sv[3];     \
        }                                                                       \
        f32x16 acc0, acc1;                                                      \
        _Pragma("unroll")                                                       \
        for (int r = 0; r < 16; ++r) { acc0[r] = 0.f; acc1[r] = 0.f; }          \
        __builtin_amdgcn_s_setprio(1);                                          \
        MFMA_E(0)  MFMA_O(1)  MFMA_E(2)  MFMA_O(3)                              \
        MFMA_E(4)  MFMA_O(5)  MFMA_E(6)  MFMA_O(7)                              \
        MFMA_E(8)  MFMA_O(9)  MFMA_E(10) MFMA_O(11)                             \
        MFMA_E(12) MFMA_O(13) MFMA_E(14) MFMA_O(15)                             \
        __builtin_amdgcn_s_setprio(0);                                          \
        EPI5();   /* previous tile's heavy epilogue, overlaps this MFMA phase */\
        if ((JT) != diag_jt) {                                                  \
            _Pragma("unroll")                                                   \
            for (int r = 0; r < 16; ++r) svp[r] = acc0[r] + acc1[r];            \
        } else {                                                                \
            const int dd2 = i_lane - (j0c + (JT) * 32) - 4 * h;                 \
            _Pragma("unroll")                                                   \
            for (int r = 0; r < 16; ++r) {                                      \
                const int jm = (r & 3) + 8 * (r >> 2);                          \
                float v = acc0[r] + acc1[r];                                    \
                svp[r] = (dd2 == jm) ? NEG_BIG : v;                             \
            }                                                                   \
        }                                                                       \
        __syncthreads();                                                        \
    }

    for (int jt = 0; jt < NTILE; jt += 2) {
        TILE_BODY(jt, 0);
        TILE_BODY(jt + 1, BUFSZ);
    }
    EPI5();   // flush last tile's deferred epilogue
#undef TILE_BODY
#undef MFMA_E
#undef MFMA_O
#undef EPI5
#undef STAGE
#undef GLL

    float s_run = s0r + s1r;
    s_run += __shfl_xor(s_run, 32);
    {
        float o0 = __shfl_xor(b0, 32), o1 = __shfl_xor(b1, 32), o2 = __shfl_xor(b2, 32),
              o3 = __shfl_xor(b3, 32), o4 = __shfl_xor(b4, 32);
        INS5(b0, b1, b2, b3, b4, o0); INS5(b0, b1, b2, b3, b4, o1);
        INS5(b0, b1, b2, b3, b4, o2); INS5(b0, b1, b2, b3, b4, o3);
        INS5(b0, b1, b2, b3, b4, o4);
    }
    if (h == 0) {
        float* p = pstats + ((size_t)ch * N_ROWS + i_lane) * 8;
        p[0] = s_run; p[1] = b0; p[2] = b1; p[3] = b2; p[4] = b3; p[5] = b4;
        p[6] = 0.f; p[7] = 0.f;
    }
}

// ---------------- K3: per-row merge of 16 chunk partials ----------------
__global__ __launch_bounds__(128) void reduce1(const float* __restrict__ pstats,
                                               float* __restrict__ partial) {
    int row = blockIdx.x * 128 + threadIdx.x;
    float S = 0.f;
    float b0 = NEG_BIG, b1 = NEG_BIG, b2 = NEG_BIG, b3 = NEG_BIG, b4 = NEG_BIG;
#pragma unroll
    for (int c = 0; c < NCHUNK; ++c) {
        const float* p = pstats + ((size_t)c * N_ROWS + row) * 8;
        S += p[0];
        float v0 = p[1], v1 = p[2], v2 = p[3], v3 = p[4], v4 = p[5];
        INS5(b0, b1, b2, b3, b4, v0); INS5(b0, b1, b2, b3, b4, v1);
        INS5(b0, b1, b2, b3, b4, v2); INS5(b0, b1, b2, b3, b4, v3);
        INS5(b0, b1, b2, b3, b4, v4);
    }
    float e0, e1, e2, e3, e4;
    EXPRAW(e0, b0); EXPRAW(e1, b1); EXPRAW(e2, b2); EXPRAW(e3, b3); EXPRAW(e4, b4);
    float S5 = e0 + e1 + e2 + e3 + e4;
    float loss = __logf(S) - __logf(S5);
#pragma unroll
    for (int m = 1; m < 64; m <<= 1) loss += __shfl_xor(loss, m);
    __shared__ float rr[2];
    if ((threadIdx.x & 63) == 0) rr[threadIdx.x >> 6] = loss;
    __syncthreads();
    if (threadIdx.x == 0) partial[blockIdx.x] = rr[0] + rr[1];
}

// ---------------- K4: final mean ----------------
__global__ void reduce2(const float* __restrict__ partial, float* __restrict__ out) {
    float v = partial[threadIdx.x];   // 64 partials
#pragma unroll
    for (int m = 1; m < 64; m <<= 1) v += __shfl_xor(v, m);
    if (threadIdx.x == 0) out[0] = v * (1.0f / N_ROWS);
}

extern "C" void kernel_launch(void* const* d_in, const int* in_sizes, int n_in,
                              void* d_out, int out_size, void* d_ws, size_t ws_size,
                              hipStream_t stream) {
    const float* z = (const float*)d_in[0];
    float* out = (float*)d_out;
    uint8_t* zn4   = (uint8_t*)d_ws;                                     // 4 MB
    uint8_t* sbq   = (uint8_t*)d_ws + (size_t)4 * 1024 * 1024;           // 256 KB
    float* pstats  = (float*)((char*)d_ws + (size_t)4608 * 1024);        // 4 MB
    float* partial = (float*)((char*)d_ws + (size_t)13 * 1024 * 1024);   // 256 B

    norm_kernel<<<N_ROWS / 4, 256, 0, stream>>>(z, zn4, sbq);
    sim_kernel<<<64 * NCHUNK, 256, 0, stream>>>(zn4, sbq, pstats);
    reduce1<<<N_ROWS / 128, 128, 0, stream>>>(pstats, partial);
    reduce2<<<1, 64, 0, stream>>>(partial, out);
}

// Round 24
// 65.744 us; speedup vs baseline: 1.0622x; 1.0622x over previous
//
#include <hip/hip_runtime.h>
#include <stdint.h>

#define N_ROWS 8192
#define D_DIM  1024
#define NEG_BIG -1e30f
#define NCHUNK 16
#define CHUNK_J 512
#define NTILE 16              // 16 j-tiles of 32 cols per chunk
#define BUFSZ 17408           // 16 KB fp4 tile + 1 KB scale block

typedef __attribute__((ext_vector_type(16))) float f32x16;
typedef __attribute__((ext_vector_type(8)))  int   i32x8;
typedef __attribute__((ext_vector_type(4)))  int   i32x4;
typedef __attribute__((ext_vector_type(2)))  long  long2_t;

// exp(10v - 10) = exp2(v*C - C), raw v_exp_f32
#define EXPC 14.4269504089f
#define EXPRAW(dst, v) { float _a = fmaf((v), EXPC, -EXPC);                 \
    asm("v_exp_f32 %0, %1" : "=v"(dst) : "v"(_a)); }

// branchless sorted insert of v into descending 5-list, med3 form
#define INS5(b0,b1,b2,b3,b4,v) {                        \
    float _n4 = __builtin_amdgcn_fmed3f(b3, (v), b4);   \
    float _n3 = __builtin_amdgcn_fmed3f(b2, (v), b3);   \
    float _n2 = __builtin_amdgcn_fmed3f(b1, (v), b2);   \
    float _n1 = __builtin_amdgcn_fmed3f(b0, (v), b1);   \
    b0 = fmaxf(b0, (v)); b1 = _n1; b2 = _n2; b3 = _n3; b4 = _n4; }

// e2m1 encode of x (pre-scaled by inv = 2^-s): grid {0,.5,1,1.5,2,3,4,6}
static __device__ inline uint32_t enc4(float x, float inv) {
    float q = fabsf(x) * inv;
    uint32_t n = q < 0.25f ? 0u : (q < 0.75f ? 1u : (q < 1.25f ? 2u : (q < 1.75f ? 3u :
                 (q < 2.5f  ? 4u : (q < 3.5f  ? 5u : (q < 5.0f  ? 6u : 7u))))));
    return n | (x < 0.f ? 8u : 0u);
}

// ---------------- K1: normalize -> MX-fp4 (e2m1 + per-32-block E8M0) --------
__global__ __launch_bounds__(256) void norm_kernel(const float* __restrict__ z,
                                                   uint8_t* __restrict__ zn4,
                                                   uint8_t* __restrict__ sbq) {
    int wave = threadIdx.x >> 6;
    int lane = threadIdx.x & 63;
    int row  = blockIdx.x * 4 + wave;
    const float* zr = z + (size_t)row * D_DIM;
    float4 c[4];
    float ss = 0.f;
#pragma unroll
    for (int i = 0; i < 4; ++i) {
        c[i] = *(const float4*)(zr + i * 256 + lane * 4);
        ss += c[i].x*c[i].x + c[i].y*c[i].y + c[i].z*c[i].z + c[i].w*c[i].w;
    }
#pragma unroll
    for (int m = 1; m < 64; m <<= 1) ss += __shfl_xor(ss, m);
    float scale = 1.0f / fmaxf(sqrtf(ss), 1e-12f);
    const int J = row >> 5, r31 = row & 31;
    uint8_t* db = zn4 + (size_t)J * 16384;
    uint8_t* sb = sbq + (size_t)J * 1024;
#pragma unroll
    for (int i = 0; i < 4; ++i) {
        float x0 = c[i].x*scale, x1 = c[i].y*scale, x2 = c[i].z*scale, x3 = c[i].w*scale;
        float am = fmaxf(fmaxf(fabsf(x0), fabsf(x1)), fmaxf(fabsf(x2), fabsf(x3)));
        am = fmaxf(am, __shfl_xor(am, 1));
        am = fmaxf(am, __shfl_xor(am, 2));
        am = fmaxf(am, __shfl_xor(am, 4));
        uint32_t ub = __float_as_uint(am);
        int sbyte = (int)(ub >> 23) - 2 + (((ub & 0x7fffffu) > 0x400000u) ? 1 : 0);
        float inv = __uint_as_float((uint32_t)(254 - sbyte) << 23);   // 2^-s
        uint32_t pk = enc4(x0, inv) | (enc4(x1, inv) << 4)
                    | (enc4(x2, inv) << 8) | (enc4(x3, inv) << 12);
        uint32_t pko = __shfl_xor(pk, 1);          // partner lane's 16 bits
        int m  = i * 4 + (lane >> 4);
        int l2 = r31 + 32 * ((lane >> 3) & 1);
        if ((lane & 1) == 0)                        // paired 4B store
            *(uint32_t*)(db + m * 1024 + l2 * 16 + 4 * ((lane & 7) >> 1))
                = pk | (pko << 16);
        if ((lane & 7) == 0) {
            int j = lane >> 3;
            sb[(size_t)(r31 + 32 * (j & 1)) * 16 + i * 4 + (j >> 1)] = (uint8_t)sbyte;
        }
    }
}

// ---------------- K2: fused MX-fp4 sim, TWO resident i-sets, no setprio ------
// R16's structure (fastest measured: 48.9 us): 32 i-blocks (256 rows: setA =
// ib*256+w*32, setB = +128) x 16 j-chunks. Each staged A-fragment feeds 2
// MFMAs (setA+setB, accA/accB chains). setprio REMOVED: m190 shows setprio
// hurts barrier-locked kernels by stalling the co-resident block's VALU phase.
__global__ __launch_bounds__(256, 2) void sim_kernel(const uint8_t* __restrict__ zn4,
                                                     const uint8_t* __restrict__ sbq,
                                                     float* __restrict__ pstats) {
    __shared__ __align__(16) char lds[2 * BUFSZ];
    const int tid  = threadIdx.x;
    const int w    = tid >> 6;
    const int l    = tid & 63;
    const int r32  = l & 31;
    const int h    = l >> 5;
    const int ib   = blockIdx.x >> 4;
    const int ch   = blockIdx.x & 15;
    const int j0c  = ch * CHUNK_J;
    const int i_laneA = ib * 256 + w * 32 + r32;
    const int i_laneB = i_laneA + 128;
    const int IiA  = ib * 8 + w;
    const int IiB  = IiA + 4;
    const int diag_jtA = ((IiA >> 4) == ch) ? (IiA & 15) : -1;
    const int diag_jtB = ((IiB >> 4) == ch) ? (IiB & 15) : -1;
    const char* ldsr = lds + l * 16;

#define GLL(SRC, DST) __builtin_amdgcn_global_load_lds(                         \
        (const __attribute__((address_space(1))) uint32_t*)(SRC),               \
        (__attribute__((address_space(3))) uint32_t*)(DST), 16, 0, 0)

#define STAGE(JTN, BUF) {                                                       \
        const uint8_t* sD_ = zn4 + (size_t)(ch * NTILE + (JTN)) * 16384;        \
        _Pragma("unroll")                                                       \
        for (int mm = 0; mm < 4; ++mm) {                                        \
            int m_ = w * 4 + mm;                                                \
            GLL(sD_ + m_ * 1024 + l * 16, (BUF) + m_ * 1024);                   \
        }                                                                       \
        if (w == 0)                                                             \
            GLL(sbq + (size_t)(ch * NTILE + (JTN)) * 1024 + l * 16,             \
                (BUF) + 16384);                                                 \
    }

    STAGE(0, lds);

    // resident B-operands, packed pairs (even m lower 4 dwords, odd m upper)
    i32x8 bresA[8], bresB[8];
    {
        const uint8_t* rpA = zn4 + (size_t)IiA * 16384 + l * 16;
        const uint8_t* rpB = zn4 + (size_t)IiB * 16384 + l * 16;
#pragma unroll
        for (int g = 0; g < 8; ++g) {
            *(long2_t*)&bresA[g]       = *(const long2_t*)(rpA + (2 * g) * 1024);
            *((long2_t*)&bresA[g] + 1) = *(const long2_t*)(rpA + (2 * g + 1) * 1024);
            *(long2_t*)&bresB[g]       = *(const long2_t*)(rpB + (2 * g) * 1024);
            *((long2_t*)&bresB[g] + 1) = *(const long2_t*)(rpB + (2 * g + 1) * 1024);
        }
    }
    uint32_t swA_[4], swB_[4];
    {
        const uint32_t* spA = (const uint32_t*)(sbq + (size_t)IiA * 1024 + l * 16);
        const uint32_t* spB = (const uint32_t*)(sbq + (size_t)IiB * 1024 + l * 16);
        swA_[0] = spA[0]; swA_[1] = spA[1]; swA_[2] = spA[2]; swA_[3] = spA[3];
        swB_[0] = spB[0]; swB_[1] = spB[1]; swB_[2] = spB[2]; swB_[3] = spB[3];
    }

    float sumA = 0.f, sumB = 0.f;
    float a0 = NEG_BIG, a1 = NEG_BIG, a2 = NEG_BIG, a3 = NEG_BIG, a4 = NEG_BIG;
    float c0 = NEG_BIG, c1 = NEG_BIG, c2 = NEG_BIG, c3 = NEG_BIG, c4 = NEG_BIG;
    i32x8 areg = {0,0,0,0,0,0,0,0};
    i32x8 btmp = {0,0,0,0,0,0,0,0};

    __syncthreads();

// one A-fragment read feeds both sets; opsel args are literal constants
#define MFMA2_E(M) {                                                            \
        asm volatile("" : "+v"(bresA[(M) >> 1]), "+v"(bresB[(M) >> 1]));        \
        *(long2_t*)&areg = *(const long2_t*)(ldst_ + (M) * 1024);               \
        accA = __builtin_amdgcn_mfma_scale_f32_32x32x64_f8f6f4(                 \
            areg, bresA[(M) >> 1], accA, 4, 4,                                  \
            (M) & 3, sa_[(M) >> 2], (M) & 3, swA_[(M) >> 2]);                   \
        accB = __builtin_amdgcn_mfma_scale_f32_32x32x64_f8f6f4(                 \
            areg, bresB[(M) >> 1], accB, 4, 4,                                  \
            (M) & 3, sa_[(M) >> 2], (M) & 3, swB_[(M) >> 2]); }
#define MFMA2_O(M) {                                                            \
        *(long2_t*)&areg = *(const long2_t*)(ldst_ + (M) * 1024);               \
        *(long2_t*)&btmp = *((const long2_t*)&bresA[(M) >> 1] + 1);             \
        accA = __builtin_amdgcn_mfma_scale_f32_32x32x64_f8f6f4(                 \
            areg, btmp, accA, 4, 4,                                             \
            (M) & 3, sa_[(M) >> 2], (M) & 3, swA_[(M) >> 2]);                   \
        *(long2_t*)&btmp = *((const long2_t*)&bresB[(M) >> 1] + 1);             \
        accB = __builtin_amdgcn_mfma_scale_f32_32x32x64_f8f6f4(                 \
            areg, btmp, accB, 4, 4,                                             \
            (M) & 3, sa_[(M) >> 2], (M) & 3, swB_[(M) >> 2]); }

#define EPIL(JT, ACC, D0, D1, D2, D3, D4, SUM, DJT, ILANE) {                    \
        if ((JT) != (DJT)) {                                                    \
            _Pragma("unroll")                                                   \
            for (int r = 0; r < 16; ++r) {                                      \
                float v = (ACC)[r];                                             \
                INS5(D0, D1, D2, D3, D4, v);                                    \
                float e_; EXPRAW(e_, v);                                        \
                SUM += e_;                                                      \
            }                                                                   \
        } else {                                                                \
            const int dd2 = (ILANE) - (j0c + (JT) * 32) - 4 * h;                \
            _Pragma("unroll")                                                   \
            for (int r = 0; r < 16; ++r) {                                      \
                const int jm = (r & 3) + 8 * (r >> 2);                          \
                float v = (ACC)[r];                                             \
                if (dd2 == jm) v = NEG_BIG;                                     \
                INS5(D0, D1, D2, D3, D4, v);                                    \
                float e_; EXPRAW(e_, v);                                        \
                SUM += e_;                                                      \
            }                                                                   \
        }                                                                       \
    }

#define TILE_BODY(JT, CUR) {                                                    \
        if ((JT) + 1 < NTILE) STAGE((JT) + 1, lds + ((CUR) ^ BUFSZ));           \
        const char* ldst_ = ldsr + (CUR);                                       \
        uint32_t sa_[4];                                                        \
        {                                                                       \
            i32x4 sv = *(const i32x4*)(lds + (CUR) + 16384 + l * 16);           \
            sa_[0] = sv[0]; sa_[1] = sv[1]; sa_[2] = sv[2]; sa_[3] = sv[3];     \
        }                                                                       \
        f32x16 accA, accB;                                                      \
        _Pragma("unroll")                                                       \
        for (int r = 0; r < 16; ++r) { accA[r] = 0.f; accB[r] = 0.f; }          \
        MFMA2_E(0)  MFMA2_O(1)  MFMA2_E(2)  MFMA2_O(3)                          \
        MFMA2_E(4)  MFMA2_O(5)  MFMA2_E(6)  MFMA2_O(7)                          \
        MFMA2_E(8)  MFMA2_O(9)  MFMA2_E(10) MFMA2_O(11)                         \
        MFMA2_E(12) MFMA2_O(13) MFMA2_E(14) MFMA2_O(15)                         \
        EPIL(JT, accA, a0, a1, a2, a3, a4, sumA, diag_jtA, i_laneA)             \
        EPIL(JT, accB, c0, c1, c2, c3, c4, sumB, diag_jtB, i_laneB)             \
        __syncthreads();                                                        \
    }

    for (int jt = 0; jt < NTILE; jt += 2) {
        TILE_BODY(jt, 0);
        TILE_BODY(jt + 1, BUFSZ);
    }
#undef TILE_BODY
#undef EPIL
#undef MFMA2_E
#undef MFMA2_O
#undef STAGE
#undef GLL

    // merge the two h-halves (lanes l, l^32 hold complementary j-rows)
    sumA += __shfl_xor(sumA, 32);
    sumB += __shfl_xor(sumB, 32);
    {
        float o0 = __shfl_xor(a0, 32), o1 = __shfl_xor(a1, 32), o2 = __shfl_xor(a2, 32),
              o3 = __shfl_xor(a3, 32), o4 = __shfl_xor(a4, 32);
        INS5(a0, a1, a2, a3, a4, o0); INS5(a0, a1, a2, a3, a4, o1);
        INS5(a0, a1, a2, a3, a4, o2); INS5(a0, a1, a2, a3, a4, o3);
        INS5(a0, a1, a2, a3, a4, o4);
    }
    {
        float o0 = __shfl_xor(c0, 32), o1 = __shfl_xor(c1, 32), o2 = __shfl_xor(c2, 32),
              o3 = __shfl_xor(c3, 32), o4 = __shfl_xor(c4, 32);
        INS5(c0, c1, c2, c3, c4, o0); INS5(c0, c1, c2, c3, c4, o1);
        INS5(c0, c1, c2, c3, c4, o2); INS5(c0, c1, c2, c3, c4, o3);
        INS5(c0, c1, c2, c3, c4, o4);
    }
    if (h == 0) {
        float* p = pstats + ((size_t)ch * N_ROWS + i_laneA) * 8;
        p[0] = sumA; p[1] = a0; p[2] = a1; p[3] = a2; p[4] = a3; p[5] = a4;
        p[6] = 0.f; p[7] = 0.f;
        float* q = pstats + ((size_t)ch * N_ROWS + i_laneB) * 8;
        q[0] = sumB; q[1] = c0; q[2] = c1; q[3] = c2; q[4] = c3; q[5] = c4;
        q[6] = 0.f; q[7] = 0.f;
    }
}

// ---------------- K3: per-row merge of 16 chunk partials ----------------
__global__ __launch_bounds__(128) void reduce1(const float* __restrict__ pstats,
                                               float* __restrict__ partial) {
    int row = blockIdx.x * 128 + threadIdx.x;
    float S = 0.f;
    float b0 = NEG_BIG, b1 = NEG_BIG, b2 = NEG_BIG, b3 = NEG_BIG, b4 = NEG_BIG;
#pragma unroll
    for (int c = 0; c < NCHUNK; ++c) {
        const float* p = pstats + ((size_t)c * N_ROWS + row) * 8;
        S += p[0];
        float v0 = p[1], v1 = p[2], v2 = p[3], v3 = p[4], v4 = p[5];
        INS5(b0, b1, b2, b3, b4, v0); INS5(b0, b1, b2, b3, b4, v1);
        INS5(b0, b1, b2, b3, b4, v2); INS5(b0, b1, b2, b3, b4, v3);
        INS5(b0, b1, b2, b3, b4, v4);
    }
    float e0, e1, e2, e3, e4;
    EXPRAW(e0, b0); EXPRAW(e1, b1); EXPRAW(e2, b2); EXPRAW(e3, b3); EXPRAW(e4, b4);
    float S5 = e0 + e1 + e2 + e3 + e4;
    float loss = __logf(S) - __logf(S5);
#pragma unroll
    for (int m = 1; m < 64; m <<= 1) loss += __shfl_xor(loss, m);
    __shared__ float rr[2];
    if ((threadIdx.x & 63) == 0) rr[threadIdx.x >> 6] = loss;
    __syncthreads();
    if (threadIdx.x == 0) partial[blockIdx.x] = rr[0] + rr[1];
}

// ---------------- K4: final mean ----------------
__global__ void reduce2(const float* __restrict__ partial, float* __restrict__ out) {
    float v = partial[threadIdx.x];   // 64 partials
#pragma unroll
    for (int m = 1; m < 64; m <<= 1) v += __shfl_xor(v, m);
    if (threadIdx.x == 0) out[0] = v * (1.0f / N_ROWS);
}

extern "C" void kernel_launch(void* const* d_in, const int* in_sizes, int n_in,
                              void* d_out, int out_size, void* d_ws, size_t ws_size,
                              hipStream_t stream) {
    const float* z = (const float*)d_in[0];
    float* out = (float*)d_out;
    uint8_t* zn4   = (uint8_t*)d_ws;                                     // 4 MB
    uint8_t* sbq   = (uint8_t*)d_ws + (size_t)4 * 1024 * 1024;           // 256 KB
    float* pstats  = (float*)((char*)d_ws + (size_t)4608 * 1024);        // 4 MB
    float* partial = (float*)((char*)d_ws + (size_t)13 * 1024 * 1024);   // 256 B

    norm_kernel<<<N_ROWS / 4, 256, 0, stream>>>(z, zn4, sbq);
    sim_kernel<<<32 * NCHUNK, 256, 0, stream>>>(zn4, sbq, pstats);
    reduce1<<<N_ROWS / 128, 128, 0, stream>>>(pstats, partial);
    reduce2<<<1, 64, 0, stream>>>(partial, out);
}